// Round 1
// baseline (4990.401 us; speedup 1.0000x reference)
//
#include <hip/hip_runtime.h>

#define NROWS 8192
#define V 20
#define C 128
#define T 64
#define HDIM 192
#define DEPTH 3

// ---------- small helpers ----------
__device__ __forceinline__ float bf2f(unsigned short u) {
    union { unsigned int i; float f; } c; c.i = ((unsigned int)u) << 16; return c.f;
}
__device__ __forceinline__ unsigned short f2bf(float f) {
    union { float f; unsigned int i; } c; c.f = f;
    unsigned int r = c.i + 0x7fffu + ((c.i >> 16) & 1u);  // RNE
    return (unsigned short)(r >> 16);
}
__device__ __forceinline__ float gelu(float x) {
    return 0.5f * x * (1.0f + erff(x * 0.70710678118654752440f));
}

// ---------- register-blocked 4x8 GEMM tiles ----------
// A: LDS, rows stride LDA, pre-offset to row r0. W: global [K][N], pre-offset to col c0.
template<int K, int LDA, int N>
__device__ __forceinline__ void gemm_bf(const unsigned short* __restrict__ A,
                                        const float* __restrict__ W,
                                        float acc[4][8])
{
#pragma unroll 2
    for (int k = 0; k < K; k += 4) {
        float a[4][4];
#pragma unroll
        for (int i = 0; i < 4; ++i) {
            ushort4 raw = *(const ushort4*)(A + i * LDA + k);
            a[i][0] = bf2f(raw.x); a[i][1] = bf2f(raw.y);
            a[i][2] = bf2f(raw.z); a[i][3] = bf2f(raw.w);
        }
#pragma unroll
        for (int kk = 0; kk < 4; ++kk) {
            const float* wr = W + (k + kk) * N;
            float4 w0 = *(const float4*)(wr);
            float4 w1 = *(const float4*)(wr + 4);
#pragma unroll
            for (int i = 0; i < 4; ++i) {
                acc[i][0] = fmaf(a[i][kk], w0.x, acc[i][0]);
                acc[i][1] = fmaf(a[i][kk], w0.y, acc[i][1]);
                acc[i][2] = fmaf(a[i][kk], w0.z, acc[i][2]);
                acc[i][3] = fmaf(a[i][kk], w0.w, acc[i][3]);
                acc[i][4] = fmaf(a[i][kk], w1.x, acc[i][4]);
                acc[i][5] = fmaf(a[i][kk], w1.y, acc[i][5]);
                acc[i][6] = fmaf(a[i][kk], w1.z, acc[i][6]);
                acc[i][7] = fmaf(a[i][kk], w1.w, acc[i][7]);
            }
        }
    }
}

template<int K, int LDA, int N>
__device__ __forceinline__ void gemm_f32(const float* __restrict__ A,
                                         const float* __restrict__ W,
                                         float acc[4][8])
{
#pragma unroll
    for (int k = 0; k < K; k += 4) {
        float a[4][4];
#pragma unroll
        for (int i = 0; i < 4; ++i) {
            float4 v = *(const float4*)(A + i * LDA + k);
            a[i][0] = v.x; a[i][1] = v.y; a[i][2] = v.z; a[i][3] = v.w;
        }
#pragma unroll
        for (int kk = 0; kk < 4; ++kk) {
            const float* wr = W + (k + kk) * N;
            float4 w0 = *(const float4*)(wr);
            float4 w1 = *(const float4*)(wr + 4);
#pragma unroll
            for (int i = 0; i < 4; ++i) {
                acc[i][0] = fmaf(a[i][kk], w0.x, acc[i][0]);
                acc[i][1] = fmaf(a[i][kk], w0.y, acc[i][1]);
                acc[i][2] = fmaf(a[i][kk], w0.z, acc[i][2]);
                acc[i][3] = fmaf(a[i][kk], w0.w, acc[i][3]);
                acc[i][4] = fmaf(a[i][kk], w1.x, acc[i][4]);
                acc[i][5] = fmaf(a[i][kk], w1.y, acc[i][5]);
                acc[i][6] = fmaf(a[i][kk], w1.z, acc[i][6]);
                acc[i][7] = fmaf(a[i][kk], w1.w, acc[i][7]);
            }
        }
    }
}

// LN over C=128 per token; 4 threads/token (tid = 4*t + part).
__device__ __forceinline__ void layer_norm_to(const float* __restrict__ sF,
                                              unsigned short* __restrict__ sA,
                                              const float* __restrict__ w,
                                              const float* __restrict__ b,
                                              int tid, bool transposed)
{
    const int t = tid >> 2, part = tid & 3;
    const float* row = sF + t * 132 + part * 32;
    float s = 0.f, q = 0.f;
#pragma unroll
    for (int j = 0; j < 8; ++j) {
        float4 v = *(const float4*)(row + j * 4);
        s += (v.x + v.y) + (v.z + v.w);
        q += v.x * v.x + v.y * v.y + v.z * v.z + v.w * v.w;
    }
    s += __shfl_xor(s, 1); q += __shfl_xor(q, 1);
    s += __shfl_xor(s, 2); q += __shfl_xor(q, 2);
    const float m = s * (1.f / 128.f);
    const float rs = rsqrtf(q * (1.f / 128.f) - m * m + 1e-5f);
#pragma unroll
    for (int j = 0; j < 32; ++j) {
        const int c = part * 32 + j;
        const float y = (sF[t * 132 + c] - m) * rs * w[c] + b[c];
        if (transposed) sA[c * 68 + t] = f2bf(y);
        else            sA[t * 132 + c] = f2bf(y);
    }
}

__global__ __launch_bounds__(256, 3)
void lanefusion_kernel(
    const float* __restrict__ x,
    const float* __restrict__ tl_table, const float* __restrict__ lane_table,
    const float* __restrict__ ch_fc1_w, const float* __restrict__ ch_fc1_b,
    const float* __restrict__ ch_fc2_w, const float* __restrict__ ch_fc2_b,
    const float* __restrict__ tok_fc1_w, const float* __restrict__ tok_fc1_b,
    const float* __restrict__ tok_fc2_w, const float* __restrict__ tok_fc2_b,
    const float* __restrict__ bn1w, const float* __restrict__ bn1b,
    const float* __restrict__ btok1w, const float* __restrict__ btok1b,
    const float* __restrict__ btok2w, const float* __restrict__ btok2b,
    const float* __restrict__ bn2w, const float* __restrict__ bn2b,
    const float* __restrict__ bch1w, const float* __restrict__ bch1b,
    const float* __restrict__ bch2w, const float* __restrict__ bch2b,
    const float* __restrict__ norm_w, const float* __restrict__ norm_b,
    const float* __restrict__ emb1w, const float* __restrict__ emb1b,
    const float* __restrict__ emb2w, const float* __restrict__ emb2b,
    float* __restrict__ out)
{
    __shared__ float sF[T * 132];            // residual stream, fp32, padded stride
    __shared__ unsigned short sA[8704];      // bf16 scratch: [C][68] or [T][132]
    __shared__ float sVec[320];              // fm/fnorm [0..127], e1 [128..319]; aliases sX/sG early
    __shared__ int sTL[V], sLT[V], sMaskV[V];
    __shared__ float sValidF;

    const int tid = threadIdx.x;
    const int r = blockIdx.x;

    float* outp  = out;
    float* maskp = out + (size_t)NROWS * HDIM;
    float* posp  = maskp + NROWS;

    float* sX = sVec;        // [100]
    float* sG = sVec + 128;  // [80]

    const float* xr = x + (size_t)r * (V * 5);
    if (tid < V * 5) sX[tid] = xr[tid];
    __syncthreads();

    if (tid < V) {
        float x0 = sX[tid * 5 + 0], x1 = sX[tid * 5 + 1], hd = sX[tid * 5 + 2];
        float chv = cosf(hd), shv = sinf(hd);
        sG[tid * 4 + 0] = x0; sG[tid * 4 + 1] = x1;
        sG[tid * 4 + 2] = chv; sG[tid * 4 + 3] = shv;
        int nz = (x0 != 0.f) + (x1 != 0.f) + (chv != 0.f) + (shv != 0.f);
        sMaskV[tid] = (nz == 0);
        int tl = (int)sX[tid * 5 + 3]; tl = tl < 0 ? 0 : (tl > 8 ? 8 : tl);
        int lt = (int)sX[tid * 5 + 4]; lt = lt < 0 ? 0 : (lt > 19 ? 19 : lt);
        sTL[tid] = tl; sLT[tid] = lt;
    }
    __syncthreads();

    if (tid == 0) {
        int mp = 1;
        for (int v = 0; v < V; ++v) mp &= sMaskV[v];
        sValidF = mp ? 0.f : 1.f;
        maskp[r] = mp ? 1.f : 0.f;
        posp[(size_t)r * 5 + 0] = sX[50];
        posp[(size_t)r * 5 + 1] = sX[51];
        posp[(size_t)r * 5 + 2] = sX[52];
        posp[(size_t)r * 5 + 3] = sX[53] * (1.f / 8.f);
        posp[(size_t)r * 5 + 4] = sX[54] * (1.f / 19.f);
    }

    // h0 = gelu(g @ ch_fc1 + b1) -> sA[v*132 + c]
    if (tid < 160) {
        const int v = tid >> 3, c0 = (tid & 7) * 16;
        const float g0 = sG[v * 4 + 0], g1 = sG[v * 4 + 1],
                    g2 = sG[v * 4 + 2], g3 = sG[v * 4 + 3];
#pragma unroll
        for (int j = 0; j < 16; ++j) {
            const int c = c0 + j;
            float s = ch_fc1_b[c];
            s = fmaf(g0, ch_fc1_w[0 * C + c], s);
            s = fmaf(g1, ch_fc1_w[1 * C + c], s);
            s = fmaf(g2, ch_fc1_w[2 * C + c], s);
            s = fmaf(g3, ch_fc1_w[3 * C + c], s);
            sA[v * 132 + c] = f2bf(gelu(s));
        }
    }
    __syncthreads();

    // f0 = h0 @ ch_fc2 + b2 + tables -> sF[c*20 + v]  (f0^T)
    if (tid < 160) {
        const int v = tid >> 3, c0 = (tid & 7) * 16;
        float acc[16];
#pragma unroll
        for (int j = 0; j < 16; ++j) acc[j] = 0.f;
        const unsigned short* Arow = sA + v * 132;
        for (int k = 0; k < C; k += 4) {
            ushort4 raw = *(const ushort4*)(Arow + k);
            float a4[4] = { bf2f(raw.x), bf2f(raw.y), bf2f(raw.z), bf2f(raw.w) };
#pragma unroll
            for (int kk = 0; kk < 4; ++kk) {
                const float* wr = ch_fc2_w + (k + kk) * C + c0;
                float4 w0 = *(const float4*)(wr);
                float4 w1 = *(const float4*)(wr + 4);
                float4 w2 = *(const float4*)(wr + 8);
                float4 w3 = *(const float4*)(wr + 12);
                acc[0]  = fmaf(a4[kk], w0.x, acc[0]);  acc[1]  = fmaf(a4[kk], w0.y, acc[1]);
                acc[2]  = fmaf(a4[kk], w0.z, acc[2]);  acc[3]  = fmaf(a4[kk], w0.w, acc[3]);
                acc[4]  = fmaf(a4[kk], w1.x, acc[4]);  acc[5]  = fmaf(a4[kk], w1.y, acc[5]);
                acc[6]  = fmaf(a4[kk], w1.z, acc[6]);  acc[7]  = fmaf(a4[kk], w1.w, acc[7]);
                acc[8]  = fmaf(a4[kk], w2.x, acc[8]);  acc[9]  = fmaf(a4[kk], w2.y, acc[9]);
                acc[10] = fmaf(a4[kk], w2.z, acc[10]); acc[11] = fmaf(a4[kk], w2.w, acc[11]);
                acc[12] = fmaf(a4[kk], w3.x, acc[12]); acc[13] = fmaf(a4[kk], w3.y, acc[13]);
                acc[14] = fmaf(a4[kk], w3.z, acc[14]); acc[15] = fmaf(a4[kk], w3.w, acc[15]);
            }
        }
        const int tl = sTL[v], lt = sLT[v];
#pragma unroll
        for (int j = 0; j < 16; ++j) {
            const int c = c0 + j;
            sF[c * 20 + v] = acc[j] + ch_fc2_b[c] + tl_table[tl * C + c] + lane_table[lt * C + c];
        }
    }
    __syncthreads();

    // token expand fc1: [C][20] @ [20][64] -> gelu -> sA[c*68 + t]
    {
        const int r0 = (tid >> 3) * 4, c0 = (tid & 7) * 8;
        float acc[4][8] = {};
        gemm_f32<20, 20, 64>(sF + r0 * 20, tok_fc1_w + c0, acc);
#pragma unroll
        for (int i = 0; i < 4; ++i)
#pragma unroll
            for (int j = 0; j < 8; ++j)
                sA[(r0 + i) * 68 + c0 + j] = f2bf(gelu(acc[i][j] + tok_fc1_b[c0 + j]));
    }
    __syncthreads();

    // token expand fc2: [C][64] @ [64][64] -> sF[t*132 + c]
    {
        const int r0 = (tid >> 3) * 4, c0 = (tid & 7) * 8;
        float acc[4][8] = {};
        gemm_bf<64, 68, 64>(sA + r0 * 68, tok_fc2_w + c0, acc);
#pragma unroll
        for (int i = 0; i < 4; ++i)
#pragma unroll
            for (int j = 0; j < 8; ++j)
                sF[(c0 + j) * 132 + (r0 + i)] = acc[i][j] + tok_fc2_b[c0 + j];
    }
    __syncthreads();

    for (int blk = 0; blk < DEPTH; ++blk) {
        layer_norm_to(sF, sA, bn1w + blk * C, bn1b + blk * C, tid, true);
        __syncthreads();
        {
            const int r0 = (tid >> 3) * 4, c0 = (tid & 7) * 8;
            float acc[4][8] = {};
            gemm_bf<64, 68, 64>(sA + r0 * 68, btok1w + blk * T * T + c0, acc);
#pragma unroll
            for (int i = 0; i < 4; ++i)
#pragma unroll
                for (int j = 0; j < 8; ++j)
                    acc[i][j] = gelu(acc[i][j] + btok1b[blk * T + c0 + j]);
            __syncthreads();
#pragma unroll
            for (int i = 0; i < 4; ++i)
#pragma unroll
                for (int j = 0; j < 8; ++j)
                    sA[(r0 + i) * 68 + c0 + j] = f2bf(acc[i][j]);
        }
        __syncthreads();
        {
            const int r0 = (tid >> 3) * 4, c0 = (tid & 7) * 8;
            float acc[4][8] = {};
            gemm_bf<64, 68, 64>(sA + r0 * 68, btok2w + blk * T * T + c0, acc);
#pragma unroll
            for (int i = 0; i < 4; ++i)
#pragma unroll
                for (int j = 0; j < 8; ++j)
                    sF[(c0 + j) * 132 + (r0 + i)] += acc[i][j] + btok2b[blk * T + c0 + j];
        }
        __syncthreads();

        layer_norm_to(sF, sA, bn2w + blk * C, bn2b + blk * C, tid, false);
        __syncthreads();
        {
            const int r0 = (tid >> 4) * 4, c0 = (tid & 15) * 8;
            float acc[4][8] = {};
            gemm_bf<128, 132, 128>(sA + r0 * 132, bch1w + blk * C * C + c0, acc);
#pragma unroll
            for (int i = 0; i < 4; ++i)
#pragma unroll
                for (int j = 0; j < 8; ++j)
                    acc[i][j] = gelu(acc[i][j] + bch1b[blk * C + c0 + j]);
            __syncthreads();
#pragma unroll
            for (int i = 0; i < 4; ++i)
#pragma unroll
                for (int j = 0; j < 8; ++j)
                    sA[(r0 + i) * 132 + c0 + j] = f2bf(acc[i][j]);
        }
        __syncthreads();
        {
            const int r0 = (tid >> 4) * 4, c0 = (tid & 15) * 8;
            float acc[4][8] = {};
            gemm_bf<128, 132, 128>(sA + r0 * 132, bch2w + blk * C * C + c0, acc);
#pragma unroll
            for (int i = 0; i < 4; ++i)
#pragma unroll
                for (int j = 0; j < 8; ++j)
                    sF[(r0 + i) * 132 + c0 + j] += acc[i][j] + bch2b[blk * C + c0 + j];
        }
        __syncthreads();
    }

    // mean over tokens + final LN (in sVec)
    float fm = 0.f;
    if (tid < C) {
#pragma unroll 8
        for (int t = 0; t < T; ++t) fm += sF[t * 132 + tid];
        fm *= (1.f / 64.f);
        sVec[tid] = fm;
    }
    __syncthreads();
    {
        float s = 0.f, q = 0.f;
        for (int c = 0; c < C; ++c) { float v = sVec[c]; s += v; q += v * v; }
        __syncthreads();
        const float m = s * (1.f / 128.f);
        const float rs = rsqrtf(q * (1.f / 128.f) - m * m + 1e-5f);
        if (tid < C) sVec[tid] = (fm - m) * rs * norm_w[tid] + norm_b[tid];
    }
    __syncthreads();

    if (tid < HDIM) {
        float s1 = emb1b[tid];
        for (int c = 0; c < C; ++c) s1 = fmaf(sVec[c], emb1w[c * HDIM + tid], s1);
        sVec[C + tid] = gelu(s1);
    }
    __syncthreads();
    if (tid < HDIM) {
        float s2 = emb2b[tid];
        for (int j = 0; j < HDIM; ++j) s2 = fmaf(sVec[C + j], emb2w[j * HDIM + tid], s2);
        outp[(size_t)r * HDIM + tid] = s2 * sValidF;
    }
}

extern "C" void kernel_launch(void* const* d_in, const int* in_sizes, int n_in,
                              void* d_out, int out_size, void* d_ws, size_t ws_size,
                              hipStream_t stream) {
    (void)in_sizes; (void)n_in; (void)out_size; (void)d_ws; (void)ws_size;
    lanefusion_kernel<<<dim3(NROWS), dim3(256), 0, stream>>>(
        (const float*)d_in[0],  (const float*)d_in[1],  (const float*)d_in[2],
        (const float*)d_in[3],  (const float*)d_in[4],  (const float*)d_in[5],
        (const float*)d_in[6],  (const float*)d_in[7],  (const float*)d_in[8],
        (const float*)d_in[9],  (const float*)d_in[10], (const float*)d_in[11],
        (const float*)d_in[12], (const float*)d_in[13], (const float*)d_in[14],
        (const float*)d_in[15], (const float*)d_in[16], (const float*)d_in[17],
        (const float*)d_in[18], (const float*)d_in[19], (const float*)d_in[20],
        (const float*)d_in[21], (const float*)d_in[22], (const float*)d_in[23],
        (const float*)d_in[24], (const float*)d_in[25], (const float*)d_in[26],
        (const float*)d_in[27], (const float*)d_in[28],
        (float*)d_out);
}

// Round 3
// 1739.195 us; speedup vs baseline: 2.8694x; 2.8694x over previous
//
#include <hip/hip_runtime.h>

#define NROWS 8192
#define V 20
#define C 128
#define T 64
#define HDIM 192
#define DEPTH 3

typedef __attribute__((ext_vector_type(8))) short bf16x8;
typedef __attribute__((ext_vector_type(4))) float floatx4;

// ---- ws segment offsets (bf16 elements), all W^T [N][K] ----
#define WS_TOKFC1 0        // [64][32]  (k>=20 zero-padded)
#define WS_TOKFC2 2048     // [64][64]
#define WS_BTOK1  6144     // [3][64][64]
#define WS_BTOK2  18432    // [3][64][64]
#define WS_CHFC2  30720    // [128][128]
#define WS_BCH1   47104    // [3][128][128]
#define WS_BCH2   96256    // [3][128][128]
#define WS_TOTAL  145408   // elements -> 290816 bytes

// ---------- helpers ----------
__device__ __forceinline__ float bf2f(unsigned short u) {
    union { unsigned int i; float f; } c; c.i = ((unsigned int)u) << 16; return c.f;
}
__device__ __forceinline__ unsigned short f2bf(float f) {
    union { float f; unsigned int i; } c; c.f = f;
    unsigned int r = c.i + 0x7fffu + ((c.i >> 16) & 1u);  // RNE
    return (unsigned short)(r >> 16);
}
__device__ __forceinline__ float gelu(float x) {
    return 0.5f * x * (1.0f + erff(x * 0.70710678118654752440f));
}
__device__ __forceinline__ floatx4 mfma16(bf16x8 a, bf16x8 b, floatx4 c) {
    return __builtin_amdgcn_mfma_f32_16x16x32_bf16(a, b, c, 0, 0, 0);
}

// LN over C=128 per token; 4 threads/token (tid = 4*t + part).
__device__ __forceinline__ void layer_norm_to(const float* __restrict__ sF,
                                              unsigned short* __restrict__ sA,
                                              const float* __restrict__ w,
                                              const float* __restrict__ b,
                                              int tid, bool transposed, int strideOut)
{
    const int t = tid >> 2, part = tid & 3;
    const float* row = sF + t * 132 + part * 32;
    float s = 0.f, q = 0.f;
#pragma unroll
    for (int j = 0; j < 8; ++j) {
        float4 v = *(const float4*)(row + j * 4);
        s += (v.x + v.y) + (v.z + v.w);
        q += v.x * v.x + v.y * v.y + v.z * v.z + v.w * v.w;
    }
    s += __shfl_xor(s, 1); q += __shfl_xor(q, 1);
    s += __shfl_xor(s, 2); q += __shfl_xor(q, 2);
    const float m = s * (1.f / 128.f);
    const float rs = rsqrtf(q * (1.f / 128.f) - m * m + 1e-5f);
#pragma unroll
    for (int j = 0; j < 32; ++j) {
        const int c = part * 32 + j;
        const float y = (sF[t * 132 + c] - m) * rs * w[c] + b[c];
        if (transposed) sA[c * strideOut + t] = f2bf(y);
        else            sA[t * strideOut + c] = f2bf(y);
    }
}

// ---------- prep: fp32 [K][N] -> bf16 W^T [N][K] in ws ----------
__global__ void prep_weights(const float* __restrict__ tokfc1,
                             const float* __restrict__ tokfc2,
                             const float* __restrict__ btok1,
                             const float* __restrict__ btok2,
                             const float* __restrict__ chfc2,
                             const float* __restrict__ bch1,
                             const float* __restrict__ bch2,
                             unsigned short* __restrict__ ws)
{
    int idx = blockIdx.x * 256 + threadIdx.x;
    if (idx >= WS_TOTAL) return;
    if (idx < 2048) {                                   // tokfc1T [64][32]
        int n = idx >> 5, k = idx & 31;
        ws[WS_TOKFC1 + idx] = (k < V) ? f2bf(tokfc1[k * 64 + n]) : 0;
        return;
    }
    idx -= 2048;
    if (idx < 4096) {                                   // tokfc2T [64][64]
        int n = idx >> 6, k = idx & 63;
        ws[WS_TOKFC2 + idx] = f2bf(tokfc2[k * 64 + n]);
        return;
    }
    idx -= 4096;
    if (idx < 12288) {                                  // btok1T [3][64][64]
        int d = idx >> 12, rem = idx & 4095, n = rem >> 6, k = rem & 63;
        ws[WS_BTOK1 + idx] = f2bf(btok1[d * 4096 + k * 64 + n]);
        return;
    }
    idx -= 12288;
    if (idx < 12288) {                                  // btok2T [3][64][64]
        int d = idx >> 12, rem = idx & 4095, n = rem >> 6, k = rem & 63;
        ws[WS_BTOK2 + idx] = f2bf(btok2[d * 4096 + k * 64 + n]);
        return;
    }
    idx -= 12288;
    if (idx < 16384) {                                  // chfc2T [128][128]
        int n = idx >> 7, k = idx & 127;
        ws[WS_CHFC2 + idx] = f2bf(chfc2[k * 128 + n]);
        return;
    }
    idx -= 16384;
    if (idx < 49152) {                                  // bch1T [3][128][128]
        int d = idx >> 14, rem = idx & 16383, n = rem >> 7, k = rem & 127;
        ws[WS_BCH1 + idx] = f2bf(bch1[d * 16384 + k * 128 + n]);
        return;
    }
    idx -= 49152;
    {                                                   // bch2T [3][128][128]
        int d = idx >> 14, rem = idx & 16383, n = rem >> 7, k = rem & 127;
        ws[WS_BCH2 + idx] = f2bf(bch2[d * 16384 + k * 128 + n]);
    }
}

// ---------- MFMA main kernel ----------
__global__ __launch_bounds__(256, 3)
void lanefusion_mfma(
    const float* __restrict__ x,
    const float* __restrict__ tl_table, const float* __restrict__ lane_table,
    const float* __restrict__ ch_fc1_w, const float* __restrict__ ch_fc1_b,
    const float* __restrict__ ch_fc2_b,
    const float* __restrict__ tok_fc1_b, const float* __restrict__ tok_fc2_b,
    const float* __restrict__ bn1w, const float* __restrict__ bn1b,
    const float* __restrict__ btok1b, const float* __restrict__ btok2b,
    const float* __restrict__ bn2w, const float* __restrict__ bn2b,
    const float* __restrict__ bch1b, const float* __restrict__ bch2b,
    const float* __restrict__ norm_w, const float* __restrict__ norm_b,
    const float* __restrict__ emb1w, const float* __restrict__ emb1b,
    const float* __restrict__ emb2w, const float* __restrict__ emb2b,
    const unsigned short* __restrict__ ws,
    float* __restrict__ out)
{
    __shared__ float sF[T * 132];            // residual, fp32 (33792 B)
    __shared__ unsigned short s1[128 * 72];  // bf16 scratch; aliased as [64][136] (18432 B)
    __shared__ float sVec[320];              // head scratch; aliases sX/sG early
    __shared__ int sTL[V], sLT[V], sMaskV[V];
    __shared__ float sValidF;

    const int tid = threadIdx.x;
    const int r = blockIdx.x;
    const int lane = tid & 63, wid = tid >> 6;
    const int lrow = lane & 15;
    const int kq = (lane >> 4) * 8;           // k-offset within a 32-chunk
    const int rrow = (lane >> 4) * 4;         // D row base within 16-tile

    float* outp  = out;
    float* maskp = out + (size_t)NROWS * HDIM;
    float* posp  = maskp + NROWS;

    float* sX = sVec;        // [100]
    float* sG = sVec + 128;  // [80]

    // zero s1 entirely: phase B reads k in [20,32) which is never written
    // (zero-padded K); uninitialized LDS there can be NaN-patterned -> NaN*0=NaN.
    {
        uint4* p = (uint4*)s1;               // 18432 B = 1152 uint4
        uint4 z; z.x = z.y = z.z = z.w = 0u;
        for (int i = tid; i < 1152; i += 256) p[i] = z;
    }

    const float* xr = x + (size_t)r * (V * 5);
    if (tid < V * 5) sX[tid] = xr[tid];
    __syncthreads();

    if (tid < V) {
        float x0 = sX[tid * 5 + 0], x1 = sX[tid * 5 + 1], hd = sX[tid * 5 + 2];
        float chv = cosf(hd), shv = sinf(hd);
        sG[tid * 4 + 0] = x0; sG[tid * 4 + 1] = x1;
        sG[tid * 4 + 2] = chv; sG[tid * 4 + 3] = shv;
        int nz = (x0 != 0.f) + (x1 != 0.f) + (chv != 0.f) + (shv != 0.f);
        sMaskV[tid] = (nz == 0);
        int tl = (int)sX[tid * 5 + 3]; tl = tl < 0 ? 0 : (tl > 8 ? 8 : tl);
        int lt = (int)sX[tid * 5 + 4]; lt = lt < 0 ? 0 : (lt > 19 ? 19 : lt);
        sTL[tid] = tl; sLT[tid] = lt;
    }
    __syncthreads();

    if (tid == 0) {
        int mp = 1;
        for (int v = 0; v < V; ++v) mp &= sMaskV[v];
        sValidF = mp ? 0.f : 1.f;
        maskp[r] = mp ? 1.f : 0.f;
        posp[(size_t)r * 5 + 0] = sX[50];
        posp[(size_t)r * 5 + 1] = sX[51];
        posp[(size_t)r * 5 + 2] = sX[52];
        posp[(size_t)r * 5 + 3] = sX[53] * (1.f / 8.f);
        posp[(size_t)r * 5 + 4] = sX[54] * (1.f / 19.f);
    }

    // ==== Phase A: h0 = gelu(g@W1+b1) in regs; f0 = h0@chfc2 (+b+tables) -> s1[c*72+v] (f0^T bf16)
    {
        float g0[4], g1[4];
        const bool v1ok = (lrow < 4);
        const int v0 = lrow, v1 = 16 + lrow;
#pragma unroll
        for (int i = 0; i < 4; ++i) {
            g0[i] = sG[v0 * 4 + i];
            g1[i] = v1ok ? sG[v1 * 4 + i] : 0.f;
        }
        bf16x8 a0[4], a1[4];
#pragma unroll
        for (int kc = 0; kc < 4; ++kc) {
            union { unsigned short u[8]; bf16x8 v; } p0, p1;
            const int kb = kc * 32 + kq;
#pragma unroll
            for (int j = 0; j < 8; ++j) {
                const float w0 = ch_fc1_w[0 * C + kb + j];
                const float w1 = ch_fc1_w[1 * C + kb + j];
                const float w2 = ch_fc1_w[2 * C + kb + j];
                const float w3 = ch_fc1_w[3 * C + kb + j];
                const float bb = ch_fc1_b[kb + j];
                float h0 = fmaf(g0[0], w0, fmaf(g0[1], w1, fmaf(g0[2], w2, fmaf(g0[3], w3, bb))));
                p0.u[j] = f2bf(gelu(h0));
                if (v1ok) {
                    float h1 = fmaf(g1[0], w0, fmaf(g1[1], w1, fmaf(g1[2], w2, fmaf(g1[3], w3, bb))));
                    p1.u[j] = f2bf(gelu(h1));
                } else p1.u[j] = 0;
            }
            a0[kc] = p0.v; a1[kc] = p1.v;
        }
        floatx4 acc[2][2];
#pragma unroll
        for (int mt = 0; mt < 2; ++mt)
#pragma unroll
            for (int ni = 0; ni < 2; ++ni) acc[mt][ni] = {0.f, 0.f, 0.f, 0.f};
        const unsigned short* wB = ws + WS_CHFC2;
#pragma unroll
        for (int kc = 0; kc < 4; ++kc) {
#pragma unroll
            for (int ni = 0; ni < 2; ++ni) {
                const int n = (2 * wid + ni) * 16 + lrow;
                bf16x8 b = *(const bf16x8*)(wB + n * 128 + kc * 32 + kq);
                acc[0][ni] = mfma16(a0[kc], b, acc[0][ni]);
                acc[1][ni] = mfma16(a1[kc], b, acc[1][ni]);
            }
        }
#pragma unroll
        for (int ni = 0; ni < 2; ++ni) {
            const int c = (2 * wid + ni) * 16 + lrow;
            const float bb = ch_fc2_b[c];
#pragma unroll
            for (int mt = 0; mt < 2; ++mt)
#pragma unroll
                for (int rr = 0; rr < 4; ++rr) {
                    const int v = mt * 16 + rrow + rr;
                    if (v < V) {
                        float val = acc[mt][ni][rr] + bb
                                  + tl_table[sTL[v] * C + c] + lane_table[sLT[v] * C + c];
                        s1[c * 72 + v] = f2bf(val);
                    }
                }
        }
    }
    // wave-local chain: phase A wrote rows 32*wid..+31 of s1; phase B reads the same stripe.

    // ==== Phase B: expand fc1 (K=32 padded), in-place gelu into s1[c*72 + t]
    {
        bf16x8 af[2];
#pragma unroll
        for (int mt = 0; mt < 2; ++mt) {
            const int m = 32 * wid + mt * 16 + lrow;
            af[mt] = *(const bf16x8*)(s1 + m * 72 + kq);
        }
        floatx4 acc[2][4];
#pragma unroll
        for (int mt = 0; mt < 2; ++mt)
#pragma unroll
            for (int nt = 0; nt < 4; ++nt) acc[mt][nt] = {0.f, 0.f, 0.f, 0.f};
        const unsigned short* wB = ws + WS_TOKFC1;
#pragma unroll
        for (int nt = 0; nt < 4; ++nt) {
            const int n = nt * 16 + lrow;
            bf16x8 b = *(const bf16x8*)(wB + n * 32 + kq);
            acc[0][nt] = mfma16(af[0], b, acc[0][nt]);
            acc[1][nt] = mfma16(af[1], b, acc[1][nt]);
        }
#pragma unroll
        for (int nt = 0; nt < 4; ++nt) {
            const int t = nt * 16 + lrow;
            const float bb = tok_fc1_b[t];
#pragma unroll
            for (int mt = 0; mt < 2; ++mt)
#pragma unroll
                for (int rr = 0; rr < 4; ++rr) {
                    const int m = 32 * wid + mt * 16 + rrow + rr;
                    s1[m * 72 + t] = f2bf(gelu(acc[mt][nt][rr] + bb));
                }
        }
    }

    // ==== Phase C: expand fc2 (K=64) -> sF[t*132 + c]
    {
        bf16x8 ac[2][2];
#pragma unroll
        for (int mt = 0; mt < 2; ++mt)
#pragma unroll
            for (int kc = 0; kc < 2; ++kc) {
                const int m = 32 * wid + mt * 16 + lrow;
                ac[mt][kc] = *(const bf16x8*)(s1 + m * 72 + kc * 32 + kq);
            }
        floatx4 acc[2][4];
#pragma unroll
        for (int mt = 0; mt < 2; ++mt)
#pragma unroll
            for (int nt = 0; nt < 4; ++nt) acc[mt][nt] = {0.f, 0.f, 0.f, 0.f};
        const unsigned short* wB = ws + WS_TOKFC2;
#pragma unroll
        for (int nt = 0; nt < 4; ++nt) {
            const int n = nt * 16 + lrow;
#pragma unroll
            for (int kc = 0; kc < 2; ++kc) {
                bf16x8 b = *(const bf16x8*)(wB + n * 64 + kc * 32 + kq);
                acc[0][nt] = mfma16(ac[0][kc], b, acc[0][nt]);
                acc[1][nt] = mfma16(ac[1][kc], b, acc[1][nt]);
            }
        }
#pragma unroll
        for (int nt = 0; nt < 4; ++nt) {
            const int t = nt * 16 + lrow;
            const float bb = tok_fc2_b[t];
#pragma unroll
            for (int mt = 0; mt < 2; ++mt)
#pragma unroll
                for (int rr = 0; rr < 4; ++rr) {
                    const int c = 32 * wid + mt * 16 + rrow + rr;
                    sF[t * 132 + c] = acc[mt][nt][rr] + bb;
                }
        }
    }
    __syncthreads();

    // ==== Mixer blocks ====
    unsigned short* s2 = s1;   // [64][136] view
    for (int blk = 0; blk < DEPTH; ++blk) {
        layer_norm_to(sF, s1, bn1w + blk * C, bn1b + blk * C, tid, true, 72);
        __syncthreads();

        // token fc1 (gelu, in-place) then token fc2 (+residual) — wave-local
        {
            bf16x8 at[2][2];
#pragma unroll
            for (int mt = 0; mt < 2; ++mt)
#pragma unroll
                for (int kc = 0; kc < 2; ++kc) {
                    const int m = 32 * wid + mt * 16 + lrow;
                    at[mt][kc] = *(const bf16x8*)(s1 + m * 72 + kc * 32 + kq);
                }
            floatx4 acc[2][4];
#pragma unroll
            for (int mt = 0; mt < 2; ++mt)
#pragma unroll
                for (int nt = 0; nt < 4; ++nt) acc[mt][nt] = {0.f, 0.f, 0.f, 0.f};
            const unsigned short* wB = ws + WS_BTOK1 + blk * 4096;
#pragma unroll
            for (int nt = 0; nt < 4; ++nt) {
                const int n = nt * 16 + lrow;
#pragma unroll
                for (int kc = 0; kc < 2; ++kc) {
                    bf16x8 b = *(const bf16x8*)(wB + n * 64 + kc * 32 + kq);
                    acc[0][nt] = mfma16(at[0][kc], b, acc[0][nt]);
                    acc[1][nt] = mfma16(at[1][kc], b, acc[1][nt]);
                }
            }
#pragma unroll
            for (int nt = 0; nt < 4; ++nt) {
                const int t = nt * 16 + lrow;
                const float bb = btok1b[blk * T + t];
#pragma unroll
                for (int mt = 0; mt < 2; ++mt)
#pragma unroll
                    for (int rr = 0; rr < 4; ++rr) {
                        const int m = 32 * wid + mt * 16 + rrow + rr;
                        s1[m * 72 + t] = f2bf(gelu(acc[mt][nt][rr] + bb));
                    }
            }
        }
        {
            bf16x8 at[2][2];
#pragma unroll
            for (int mt = 0; mt < 2; ++mt)
#pragma unroll
                for (int kc = 0; kc < 2; ++kc) {
                    const int m = 32 * wid + mt * 16 + lrow;
                    at[mt][kc] = *(const bf16x8*)(s1 + m * 72 + kc * 32 + kq);
                }
            floatx4 acc[2][4];
#pragma unroll
            for (int mt = 0; mt < 2; ++mt)
#pragma unroll
                for (int nt = 0; nt < 4; ++nt) acc[mt][nt] = {0.f, 0.f, 0.f, 0.f};
            const unsigned short* wB = ws + WS_BTOK2 + blk * 4096;
#pragma unroll
            for (int nt = 0; nt < 4; ++nt) {
                const int n = nt * 16 + lrow;
#pragma unroll
                for (int kc = 0; kc < 2; ++kc) {
                    bf16x8 b = *(const bf16x8*)(wB + n * 64 + kc * 32 + kq);
                    acc[0][nt] = mfma16(at[0][kc], b, acc[0][nt]);
                    acc[1][nt] = mfma16(at[1][kc], b, acc[1][nt]);
                }
            }
#pragma unroll
            for (int nt = 0; nt < 4; ++nt) {
                const int t = nt * 16 + lrow;
                const float bb = btok2b[blk * T + t];
#pragma unroll
                for (int mt = 0; mt < 2; ++mt)
#pragma unroll
                    for (int rr = 0; rr < 4; ++rr) {
                        const int c = 32 * wid + mt * 16 + rrow + rr;
                        sF[t * 132 + c] += acc[mt][nt][rr] + bb;
                    }
            }
        }
        __syncthreads();

        layer_norm_to(sF, s2, bn2w + blk * C, bn2b + blk * C, tid, false, 136);
        __syncthreads();

        // channel fc1 (gelu, in-place) then channel fc2 (+residual) — wave-local
        {
            bf16x8 a2[4];
            const int m = 16 * wid + lrow;
#pragma unroll
            for (int kc = 0; kc < 4; ++kc)
                a2[kc] = *(const bf16x8*)(s2 + m * 136 + kc * 32 + kq);
            floatx4 acc[8];
#pragma unroll
            for (int nt = 0; nt < 8; ++nt) acc[nt] = {0.f, 0.f, 0.f, 0.f};
            const unsigned short* wB = ws + WS_BCH1 + blk * 16384;
#pragma unroll
            for (int nt = 0; nt < 8; ++nt) {
                const int n = nt * 16 + lrow;
#pragma unroll
                for (int kc = 0; kc < 4; ++kc) {
                    bf16x8 b = *(const bf16x8*)(wB + n * 128 + kc * 32 + kq);
                    acc[nt] = mfma16(a2[kc], b, acc[nt]);
                }
            }
#pragma unroll
            for (int nt = 0; nt < 8; ++nt) {
                const int c = nt * 16 + lrow;
                const float bb = bch1b[blk * C + c];
#pragma unroll
                for (int rr = 0; rr < 4; ++rr) {
                    const int t = 16 * wid + rrow + rr;
                    s2[t * 136 + c] = f2bf(gelu(acc[nt][rr] + bb));
                }
            }
        }
        {
            bf16x8 a2[4];
            const int m = 16 * wid + lrow;
#pragma unroll
            for (int kc = 0; kc < 4; ++kc)
                a2[kc] = *(const bf16x8*)(s2 + m * 136 + kc * 32 + kq);
            floatx4 acc[8];
#pragma unroll
            for (int nt = 0; nt < 8; ++nt) acc[nt] = {0.f, 0.f, 0.f, 0.f};
            const unsigned short* wB = ws + WS_BCH2 + blk * 16384;
#pragma unroll
            for (int nt = 0; nt < 8; ++nt) {
                const int n = nt * 16 + lrow;
#pragma unroll
                for (int kc = 0; kc < 4; ++kc) {
                    bf16x8 b = *(const bf16x8*)(wB + n * 128 + kc * 32 + kq);
                    acc[nt] = mfma16(a2[kc], b, acc[nt]);
                }
            }
#pragma unroll
            for (int nt = 0; nt < 8; ++nt) {
                const int c = nt * 16 + lrow;
                const float bb = bch2b[blk * C + c];
#pragma unroll
                for (int rr = 0; rr < 4; ++rr) {
                    const int t = 16 * wid + rrow + rr;
                    sF[t * 132 + c] += acc[nt][rr] + bb;
                }
            }
        }
        __syncthreads();
    }

    // ==== mean over tokens + final LN ====
    float fm = 0.f;
    if (tid < C) {
#pragma unroll 8
        for (int t = 0; t < T; ++t) fm += sF[t * 132 + tid];
        fm *= (1.f / 64.f);
        sVec[tid] = fm;
    }
    __syncthreads();
    {
        float s = 0.f, q = 0.f;
        for (int c = 0; c < C; ++c) { float v = sVec[c]; s += v; q += v * v; }
        __syncthreads();
        const float m = s * (1.f / 128.f);
        const float rs = rsqrtf(q * (1.f / 128.f) - m * m + 1e-5f);
        if (tid < C) sVec[tid] = (fm - m) * rs * norm_w[tid] + norm_b[tid];
    }
    __syncthreads();

    if (tid < HDIM) {
        float v1 = emb1b[tid];
        for (int c = 0; c < C; ++c) v1 = fmaf(sVec[c], emb1w[c * HDIM + tid], v1);
        sVec[C + tid] = gelu(v1);
    }
    __syncthreads();
    if (tid < HDIM) {
        float v2 = emb2b[tid];
        for (int j = 0; j < HDIM; ++j) v2 = fmaf(sVec[C + j], emb2w[j * HDIM + tid], v2);
        outp[(size_t)r * HDIM + tid] = v2 * sValidF;
    }
}

// ================= fallback scalar kernel (R1 version) =================
template<int K, int LDA, int N>
__device__ __forceinline__ void gemm_bf(const unsigned short* __restrict__ A,
                                        const float* __restrict__ W,
                                        float acc[4][8])
{
#pragma unroll 2
    for (int k = 0; k < K; k += 4) {
        float a[4][4];
#pragma unroll
        for (int i = 0; i < 4; ++i) {
            ushort4 raw = *(const ushort4*)(A + i * LDA + k);
            a[i][0] = bf2f(raw.x); a[i][1] = bf2f(raw.y);
            a[i][2] = bf2f(raw.z); a[i][3] = bf2f(raw.w);
        }
#pragma unroll
        for (int kk = 0; kk < 4; ++kk) {
            const float* wr = W + (k + kk) * N;
            float4 w0 = *(const float4*)(wr);
            float4 w1 = *(const float4*)(wr + 4);
#pragma unroll
            for (int i = 0; i < 4; ++i) {
                acc[i][0] = fmaf(a[i][kk], w0.x, acc[i][0]);
                acc[i][1] = fmaf(a[i][kk], w0.y, acc[i][1]);
                acc[i][2] = fmaf(a[i][kk], w0.z, acc[i][2]);
                acc[i][3] = fmaf(a[i][kk], w0.w, acc[i][3]);
                acc[i][4] = fmaf(a[i][kk], w1.x, acc[i][4]);
                acc[i][5] = fmaf(a[i][kk], w1.y, acc[i][5]);
                acc[i][6] = fmaf(a[i][kk], w1.z, acc[i][6]);
                acc[i][7] = fmaf(a[i][kk], w1.w, acc[i][7]);
            }
        }
    }
}

template<int K, int LDA, int N>
__device__ __forceinline__ void gemm_f32(const float* __restrict__ A,
                                         const float* __restrict__ W,
                                         float acc[4][8])
{
#pragma unroll
    for (int k = 0; k < K; k += 4) {
        float a[4][4];
#pragma unroll
        for (int i = 0; i < 4; ++i) {
            float4 v = *(const float4*)(A + i * LDA + k);
            a[i][0] = v.x; a[i][1] = v.y; a[i][2] = v.z; a[i][3] = v.w;
        }
#pragma unroll
        for (int kk = 0; kk < 4; ++kk) {
            const float* wr = W + (k + kk) * N;
            float4 w0 = *(const float4*)(wr);
            float4 w1 = *(const float4*)(wr + 4);
#pragma unroll
            for (int i = 0; i < 4; ++i) {
                acc[i][0] = fmaf(a[i][kk], w0.x, acc[i][0]);
                acc[i][1] = fmaf(a[i][kk], w0.y, acc[i][1]);
                acc[i][2] = fmaf(a[i][kk], w0.z, acc[i][2]);
                acc[i][3] = fmaf(a[i][kk], w0.w, acc[i][3]);
                acc[i][4] = fmaf(a[i][kk], w1.x, acc[i][4]);
                acc[i][5] = fmaf(a[i][kk], w1.y, acc[i][5]);
                acc[i][6] = fmaf(a[i][kk], w1.z, acc[i][6]);
                acc[i][7] = fmaf(a[i][kk], w1.w, acc[i][7]);
            }
        }
    }
}

__global__ __launch_bounds__(256, 3)
void lanefusion_scalar(
    const float* __restrict__ x,
    const float* __restrict__ tl_table, const float* __restrict__ lane_table,
    const float* __restrict__ ch_fc1_w, const float* __restrict__ ch_fc1_b,
    const float* __restrict__ ch_fc2_w, const float* __restrict__ ch_fc2_b,
    const float* __restrict__ tok_fc1_w, const float* __restrict__ tok_fc1_b,
    const float* __restrict__ tok_fc2_w, const float* __restrict__ tok_fc2_b,
    const float* __restrict__ bn1w, const float* __restrict__ bn1b,
    const float* __restrict__ btok1w, const float* __restrict__ btok1b,
    const float* __restrict__ btok2w, const float* __restrict__ btok2b,
    const float* __restrict__ bn2w, const float* __restrict__ bn2b,
    const float* __restrict__ bch1w, const float* __restrict__ bch1b,
    const float* __restrict__ bch2w, const float* __restrict__ bch2b,
    const float* __restrict__ norm_w, const float* __restrict__ norm_b,
    const float* __restrict__ emb1w, const float* __restrict__ emb1b,
    const float* __restrict__ emb2w, const float* __restrict__ emb2b,
    float* __restrict__ out)
{
    __shared__ float sF[T * 132];
    __shared__ unsigned short sA[8704];
    __shared__ float sVec[320];
    __shared__ int sTL[V], sLT[V], sMaskV[V];
    __shared__ float sValidF;

    const int tid = threadIdx.x;
    const int r = blockIdx.x;

    float* outp  = out;
    float* maskp = out + (size_t)NROWS * HDIM;
    float* posp  = maskp + NROWS;

    float* sX = sVec;
    float* sG = sVec + 128;

    const float* xr = x + (size_t)r * (V * 5);
    if (tid < V * 5) sX[tid] = xr[tid];
    __syncthreads();

    if (tid < V) {
        float x0 = sX[tid * 5 + 0], x1 = sX[tid * 5 + 1], hd = sX[tid * 5 + 2];
        float chv = cosf(hd), shv = sinf(hd);
        sG[tid * 4 + 0] = x0; sG[tid * 4 + 1] = x1;
        sG[tid * 4 + 2] = chv; sG[tid * 4 + 3] = shv;
        int nz = (x0 != 0.f) + (x1 != 0.f) + (chv != 0.f) + (shv != 0.f);
        sMaskV[tid] = (nz == 0);
        int tl = (int)sX[tid * 5 + 3]; tl = tl < 0 ? 0 : (tl > 8 ? 8 : tl);
        int lt = (int)sX[tid * 5 + 4]; lt = lt < 0 ? 0 : (lt > 19 ? 19 : lt);
        sTL[tid] = tl; sLT[tid] = lt;
    }
    __syncthreads();

    if (tid == 0) {
        int mp = 1;
        for (int v = 0; v < V; ++v) mp &= sMaskV[v];
        sValidF = mp ? 0.f : 1.f;
        maskp[r] = mp ? 1.f : 0.f;
        posp[(size_t)r * 5 + 0] = sX[50];
        posp[(size_t)r * 5 + 1] = sX[51];
        posp[(size_t)r * 5 + 2] = sX[52];
        posp[(size_t)r * 5 + 3] = sX[53] * (1.f / 8.f);
        posp[(size_t)r * 5 + 4] = sX[54] * (1.f / 19.f);
    }

    if (tid < 160) {
        const int v = tid >> 3, c0 = (tid & 7) * 16;
        const float g0 = sG[v * 4 + 0], g1 = sG[v * 4 + 1],
                    g2 = sG[v * 4 + 2], g3 = sG[v * 4 + 3];
#pragma unroll
        for (int j = 0; j < 16; ++j) {
            const int c = c0 + j;
            float s = ch_fc1_b[c];
            s = fmaf(g0, ch_fc1_w[0 * C + c], s);
            s = fmaf(g1, ch_fc1_w[1 * C + c], s);
            s = fmaf(g2, ch_fc1_w[2 * C + c], s);
            s = fmaf(g3, ch_fc1_w[3 * C + c], s);
            sA[v * 132 + c] = f2bf(gelu(s));
        }
    }
    __syncthreads();

    if (tid < 160) {
        const int v = tid >> 3, c0 = (tid & 7) * 16;
        float acc[16];
#pragma unroll
        for (int j = 0; j < 16; ++j) acc[j] = 0.f;
        const unsigned short* Arow = sA + v * 132;
        for (int k = 0; k < C; k += 4) {
            ushort4 raw = *(const ushort4*)(Arow + k);
            float a4[4] = { bf2f(raw.x), bf2f(raw.y), bf2f(raw.z), bf2f(raw.w) };
#pragma unroll
            for (int kk = 0; kk < 4; ++kk) {
                const float* wr = ch_fc2_w + (k + kk) * C + c0;
                float4 w0 = *(const float4*)(wr);
                float4 w1 = *(const float4*)(wr + 4);
                float4 w2 = *(const float4*)(wr + 8);
                float4 w3 = *(const float4*)(wr + 12);
                acc[0]  = fmaf(a4[kk], w0.x, acc[0]);  acc[1]  = fmaf(a4[kk], w0.y, acc[1]);
                acc[2]  = fmaf(a4[kk], w0.z, acc[2]);  acc[3]  = fmaf(a4[kk], w0.w, acc[3]);
                acc[4]  = fmaf(a4[kk], w1.x, acc[4]);  acc[5]  = fmaf(a4[kk], w1.y, acc[5]);
                acc[6]  = fmaf(a4[kk], w1.z, acc[6]);  acc[7]  = fmaf(a4[kk], w1.w, acc[7]);
                acc[8]  = fmaf(a4[kk], w2.x, acc[8]);  acc[9]  = fmaf(a4[kk], w2.y, acc[9]);
                acc[10] = fmaf(a4[kk], w2.z, acc[10]); acc[11] = fmaf(a4[kk], w2.w, acc[11]);
                acc[12] = fmaf(a4[kk], w3.x, acc[12]); acc[13] = fmaf(a4[kk], w3.y, acc[13]);
                acc[14] = fmaf(a4[kk], w3.z, acc[14]); acc[15] = fmaf(a4[kk], w3.w, acc[15]);
            }
        }
        const int tl = sTL[v], lt = sLT[v];
#pragma unroll
        for (int j = 0; j < 16; ++j) {
            const int c = c0 + j;
            sF[c * 20 + v] = acc[j] + ch_fc2_b[c] + tl_table[tl * C + c] + lane_table[lt * C + c];
        }
    }
    __syncthreads();

    {
        const int r0 = (tid >> 3) * 4, c0 = (tid & 7) * 8;
        float acc[4][8] = {};
        gemm_f32<20, 20, 64>(sF + r0 * 20, tok_fc1_w + c0, acc);
#pragma unroll
        for (int i = 0; i < 4; ++i)
#pragma unroll
            for (int j = 0; j < 8; ++j)
                sA[(r0 + i) * 68 + c0 + j] = f2bf(gelu(acc[i][j] + tok_fc1_b[c0 + j]));
    }
    __syncthreads();

    {
        const int r0 = (tid >> 3) * 4, c0 = (tid & 7) * 8;
        float acc[4][8] = {};
        gemm_bf<64, 68, 64>(sA + r0 * 68, tok_fc2_w + c0, acc);
#pragma unroll
        for (int i = 0; i < 4; ++i)
#pragma unroll
            for (int j = 0; j < 8; ++j)
                sF[(c0 + j) * 132 + (r0 + i)] = acc[i][j] + tok_fc2_b[c0 + j];
    }
    __syncthreads();

    for (int blk = 0; blk < DEPTH; ++blk) {
        layer_norm_to(sF, sA, bn1w + blk * C, bn1b + blk * C, tid, true, 68);
        __syncthreads();
        {
            const int r0 = (tid >> 3) * 4, c0 = (tid & 7) * 8;
            float acc[4][8] = {};
            gemm_bf<64, 68, 64>(sA + r0 * 68, btok1w + blk * T * T + c0, acc);
#pragma unroll
            for (int i = 0; i < 4; ++i)
#pragma unroll
                for (int j = 0; j < 8; ++j)
                    acc[i][j] = gelu(acc[i][j] + btok1b[blk * T + c0 + j]);
            __syncthreads();
#pragma unroll
            for (int i = 0; i < 4; ++i)
#pragma unroll
                for (int j = 0; j < 8; ++j)
                    sA[(r0 + i) * 68 + c0 + j] = f2bf(acc[i][j]);
        }
        __syncthreads();
        {
            const int r0 = (tid >> 3) * 4, c0 = (tid & 7) * 8;
            float acc[4][8] = {};
            gemm_bf<64, 68, 64>(sA + r0 * 68, btok2w + blk * T * T + c0, acc);
#pragma unroll
            for (int i = 0; i < 4; ++i)
#pragma unroll
                for (int j = 0; j < 8; ++j)
                    sF[(c0 + j) * 132 + (r0 + i)] += acc[i][j] + btok2b[blk * T + c0 + j];
        }
        __syncthreads();

        layer_norm_to(sF, sA, bn2w + blk * C, bn2b + blk * C, tid, false, 132);
        __syncthreads();
        {
            const int r0 = (tid >> 4) * 4, c0 = (tid & 15) * 8;
            float acc[4][8] = {};
            gemm_bf<128, 132, 128>(sA + r0 * 132, bch1w + blk * C * C + c0, acc);
#pragma unroll
            for (int i = 0; i < 4; ++i)
#pragma unroll
                for (int j = 0; j < 8; ++j)
                    acc[i][j] = gelu(acc[i][j] + bch1b[blk * C + c0 + j]);
            __syncthreads();
#pragma unroll
            for (int i = 0; i < 4; ++i)
#pragma unroll
                for (int j = 0; j < 8; ++j)
                    sA[(r0 + i) * 132 + c0 + j] = f2bf(acc[i][j]);
        }
        __syncthreads();
        {
            const int r0 = (tid >> 4) * 4, c0 = (tid & 15) * 8;
            float acc[4][8] = {};
            gemm_bf<128, 132, 128>(sA + r0 * 132, bch2w + blk * C * C + c0, acc);
#pragma unroll
            for (int i = 0; i < 4; ++i)
#pragma unroll
                for (int j = 0; j < 8; ++j)
                    sF[(r0 + i) * 132 + c0 + j] += acc[i][j] + bch2b[blk * C + c0 + j];
        }
        __syncthreads();
    }

    float fm = 0.f;
    if (tid < C) {
#pragma unroll 8
        for (int t = 0; t < T; ++t) fm += sF[t * 132 + tid];
        fm *= (1.f / 64.f);
        sVec[tid] = fm;
    }
    __syncthreads();
    {
        float s = 0.f, q = 0.f;
        for (int c = 0; c < C; ++c) { float v = sVec[c]; s += v; q += v * v; }
        __syncthreads();
        const float m = s * (1.f / 128.f);
        const float rs = rsqrtf(q * (1.f / 128.f) - m * m + 1e-5f);
        if (tid < C) sVec[tid] = (fm - m) * rs * norm_w[tid] + norm_b[tid];
    }
    __syncthreads();

    if (tid < HDIM) {
        float v1 = emb1b[tid];
        for (int c = 0; c < C; ++c) v1 = fmaf(sVec[c], emb1w[c * HDIM + tid], v1);
        sVec[C + tid] = gelu(v1);
    }
    __syncthreads();
    if (tid < HDIM) {
        float v2 = emb2b[tid];
        for (int j = 0; j < HDIM; ++j) v2 = fmaf(sVec[C + j], emb2w[j * HDIM + tid], v2);
        outp[(size_t)r * HDIM + tid] = v2 * sValidF;
    }
}

extern "C" void kernel_launch(void* const* d_in, const int* in_sizes, int n_in,
                              void* d_out, int out_size, void* d_ws, size_t ws_size,
                              hipStream_t stream) {
    (void)in_sizes; (void)n_in; (void)out_size;
    if (ws_size >= (size_t)WS_TOTAL * 2) {
        prep_weights<<<dim3((WS_TOTAL + 255) / 256), dim3(256), 0, stream>>>(
            (const float*)d_in[7],  // tok_fc1_w
            (const float*)d_in[9],  // tok_fc2_w
            (const float*)d_in[13], // blk_tok_fc1_w
            (const float*)d_in[15], // blk_tok_fc2_w
            (const float*)d_in[5],  // ch_fc2_w
            (const float*)d_in[19], // blk_ch_fc1_w
            (const float*)d_in[21], // blk_ch_fc2_w
            (unsigned short*)d_ws);
        lanefusion_mfma<<<dim3(NROWS), dim3(256), 0, stream>>>(
            (const float*)d_in[0],  (const float*)d_in[1],  (const float*)d_in[2],
            (const float*)d_in[3],  (const float*)d_in[4],
            (const float*)d_in[6],
            (const float*)d_in[8],  (const float*)d_in[10],
            (const float*)d_in[11], (const float*)d_in[12],
            (const float*)d_in[14], (const float*)d_in[16],
            (const float*)d_in[17], (const float*)d_in[18],
            (const float*)d_in[20], (const float*)d_in[22],
            (const float*)d_in[23], (const float*)d_in[24],
            (const float*)d_in[25], (const float*)d_in[26],
            (const float*)d_in[27], (const float*)d_in[28],
            (const unsigned short*)d_ws,
            (float*)d_out);
    } else {
        lanefusion_scalar<<<dim3(NROWS), dim3(256), 0, stream>>>(
            (const float*)d_in[0],  (const float*)d_in[1],  (const float*)d_in[2],
            (const float*)d_in[3],  (const float*)d_in[4],  (const float*)d_in[5],
            (const float*)d_in[6],  (const float*)d_in[7],  (const float*)d_in[8],
            (const float*)d_in[9],  (const float*)d_in[10], (const float*)d_in[11],
            (const float*)d_in[12], (const float*)d_in[13], (const float*)d_in[14],
            (const float*)d_in[15], (const float*)d_in[16], (const float*)d_in[17],
            (const float*)d_in[18], (const float*)d_in[19], (const float*)d_in[20],
            (const float*)d_in[21], (const float*)d_in[22], (const float*)d_in[23],
            (const float*)d_in[24], (const float*)d_in[25], (const float*)d_in[26],
            (const float*)d_in[27], (const float*)d_in[28],
            (float*)d_out);
    }
}